// Round 12
// baseline (199.439 us; speedup 1.0000x reference)
//
#include <hip/hip_runtime.h>
#include <hip/hip_bf16.h>

// Problem constants: B=2, S=4096, E=512, H=8, D=64
typedef __attribute__((ext_vector_type(8))) short bf16x8;
typedef __attribute__((ext_vector_type(4))) float f32x4;

#define MFMA16 __builtin_amdgcn_mfma_f32_16x16x32_bf16

__device__ __forceinline__ unsigned short f2bf(float f) {
  unsigned int u = __builtin_bit_cast(unsigned int, f);
  u += 0x7FFFu + ((u >> 16) & 1u);   // round-to-nearest-even
  return (unsigned short)(u >> 16);
}

__device__ __forceinline__ void load_lds16(const void* g, void* l) {
  __builtin_amdgcn_global_load_lds(
      (const __attribute__((address_space(1))) unsigned int*)g,
      (__attribute__((address_space(3))) unsigned int*)l, 16, 0, 0);
}

// ---------------------------------------------------------------------------
// Prep: x -> bf16 (row-major [8192][512]); w_qkv -> bf16 transposed [1536][512];
// w_out -> bf16 transposed [512][512].
// ---------------------------------------------------------------------------
__global__ __launch_bounds__(256) void prep_kernel(
    const float* __restrict__ x, const float* __restrict__ wqkv,
    const float* __restrict__ wout, unsigned short* __restrict__ xb,
    unsigned short* __restrict__ wqkvT, unsigned short* __restrict__ woutT) {
  int blk = blockIdx.x;
  int t = threadIdx.x;
  if (blk < 4096) {                       // x convert: 4,194,304 elems
    int i = (blk * 256 + t) * 4;
    float4 v = *(const float4*)(x + i);
    ushort4 o;
    o.x = f2bf(v.x); o.y = f2bf(v.y); o.z = f2bf(v.z); o.w = f2bf(v.w);
    *(ushort4*)(xb + i) = o;
  } else if (blk < 4864) {                // w_qkv transpose: 512 x 1536
    int u = ((blk - 4096) * 256 + t) * 4;
    int k = u / 1536, n = u % 1536;
    float4 v = *(const float4*)(wqkv + (size_t)k * 1536 + n);
    wqkvT[(size_t)(n + 0) * 512 + k] = f2bf(v.x);
    wqkvT[(size_t)(n + 1) * 512 + k] = f2bf(v.y);
    wqkvT[(size_t)(n + 2) * 512 + k] = f2bf(v.z);
    wqkvT[(size_t)(n + 3) * 512 + k] = f2bf(v.w);
  } else {                                // w_out transpose: 512 x 512
    int u = ((blk - 4864) * 256 + t) * 4;
    int k = u >> 9, n = u & 511;
    float4 v = *(const float4*)(wout + (size_t)k * 512 + n);
    woutT[(size_t)(n + 0) * 512 + k] = f2bf(v.x);
    woutT[(size_t)(n + 1) * 512 + k] = f2bf(v.y);
    woutT[(size_t)(n + 2) * 512 + k] = f2bf(v.z);
    woutT[(size_t)(n + 3) * 512 + k] = f2bf(v.w);
  }
}

// ---------------------------------------------------------------------------
// QKV GEMM (round-8 kernel, verified): 2-phase dbuf staging; epilogue via LDS
// transpose then 8 x 16B coalesced stores. Layouts identical to round 7.
// ---------------------------------------------------------------------------
__global__ __launch_bounds__(256, 2) void qkv_gemm(
    const unsigned short* __restrict__ xb, const unsigned short* __restrict__ bt,
    const float* __restrict__ bias, unsigned short* __restrict__ qout,
    unsigned short* __restrict__ ksw, unsigned short* __restrict__ vtsw) {
  __shared__ unsigned short SH[16384];   // 32KB: staging dbuf, then epilogue tile
  const int t = threadIdx.x;
  const int lane = t & 63;
  const int llo = lane & 15, lhi = lane >> 4;
  const int w = t >> 6, wr = w >> 1, wc = w & 1;
  const int m0 = blockIdx.x * 128, n0 = blockIdx.y * 128;

  f32x4 acc[4][4];
#pragma unroll
  for (int i = 0; i < 4; ++i)
#pragma unroll
    for (int j = 0; j < 4; ++j) acc[i][j] = (f32x4){0.f, 0.f, 0.f, 0.f};

  const int r0 = t >> 2;            // staging row (unit t)
  const int sb = (t & 3) * 16;      // byte seg within row (64B rows)

  auto stage = [&](int k0, int buf) {
    const char* ga = (const char*)xb + (size_t)(m0 + r0) * 1024 + k0 * 2 + sb;
    const char* gb = (const char*)bt + (size_t)(n0 + r0) * 1024 + k0 * 2 + sb;
    char* la = (char*)SH + buf * 8192;
    char* lb = (char*)SH + 16384 + buf * 8192;
    load_lds16(ga, la + t * 16);
    load_lds16(ga + 64 * 1024, la + 4096 + t * 16);
    load_lds16(gb, lb + t * 16);
    load_lds16(gb + 64 * 1024, lb + 4096 + t * 16);
  };

  stage(0, 0);
  __syncthreads();

  int cur = 0;
  for (int k0 = 0; k0 < 512; k0 += 32) {
    if (k0 + 32 < 512) stage(k0 + 32, cur ^ 1);

    const unsigned short* usA = SH + cur * 4096;
    const unsigned short* usB = SH + 8192 + cur * 4096;
    bf16x8 af[4], bf[4];
#pragma unroll
    for (int mi = 0; mi < 4; ++mi)
      af[mi] = *(const bf16x8*)(usA + (wr * 64 + mi * 16 + llo) * 32 + lhi * 8);
#pragma unroll
    for (int ni = 0; ni < 4; ++ni)
      bf[ni] = *(const bf16x8*)(usB + (wc * 64 + ni * 16 + llo) * 32 + lhi * 8);
#pragma unroll
    for (int mi = 0; mi < 4; ++mi)
#pragma unroll
      for (int ni = 0; ni < 4; ++ni)
        acc[mi][ni] = MFMA16(af[mi], bf[ni], acc[mi][ni], 0, 0, 0);
    __syncthreads();
    cur ^= 1;
  }

  // ---- epilogue phase 1: scatter into SH (layout-permuted, bank-swizzled) ----
  const int sec = n0 >> 9;               // 0=q, 1=K, 2=V (uniform per block)
  const int hbase = (n0 >> 6) & 7;
#pragma unroll
  for (int ni = 0; ni < 4; ++ni) {
    int lcol = wc * 64 + ni * 16 + llo;
    float bv = bias[n0 + lcol];
#pragma unroll
    for (int mi = 0; mi < 4; ++mi) {
#pragma unroll
      for (int r = 0; r < 4; ++r) {
        int rowm = wr * 64 + mi * 16 + lhi * 4 + r;
        float val = acc[mi][ni][r] + bv;
        unsigned short bits;
        int idx;
        if (sec == 0) {
          bits = f2bf(val * 0.18033688f);   // D^-0.5 * log2(e)
          idx = rowm * 128 + (lcol ^ ((rowm & 15) << 3));
        } else if (sec == 1) {
          bits = f2bf(val);
          idx = rowm * 128 + (lcol ^ ((rowm & 15) << 3));
        } else {
          bits = f2bf(val);
          int u64k = rowm & 63;
          int c = u64k >> 4, u = u64k & 15;
          int kperm = ((c >> 1) << 5) + ((u >> 2) << 3) + ((c & 1) << 2) + (u & 3);
          int ktile = rowm >> 6;
          idx = lcol * 128 + ((ktile * 64 + kperm) ^ ((lcol & 15) << 3));
        }
        SH[idx] = bits;
      }
    }
  }
  __syncthreads();

  // ---- epilogue phase 2: 8 x 16B coalesced stores per thread ----
  const int b = m0 >> 12;
  if (sec == 0) {
#pragma unroll
    for (int j = 0; j < 8; ++j) {
      int cidx = j * 256 + t;
      int dc = cidx & 7, srow = (cidx >> 3) & 127, h2 = cidx >> 10;
      int bh = b * 8 + hbase + h2;
      int s = (m0 & 4095) + srow;
      bf16x8 v = *(const bf16x8*)(SH + srow * 128 +
                                  ((h2 * 64 + dc * 8) ^ ((srow & 15) << 3)));
      *(bf16x8*)(qout + ((size_t)bh * 4096 + s) * 64 + dc * 8) = v;
    }
  } else if (sec == 1) {
#pragma unroll
    for (int j = 0; j < 8; ++j) {
      int cidx = j * 256 + t;
      int dc = cidx & 7, srow = (cidx >> 3) & 127, h2 = cidx >> 10;
      int bh = b * 8 + hbase + h2;
      int s = (m0 & 4095) + srow;
      bf16x8 v = *(const bf16x8*)(SH + srow * 128 +
                                  ((h2 * 64 + dc * 8) ^ ((srow & 15) << 3)));
      size_t byte = (size_t)bh * 524288 + (size_t)(s >> 6) * 8192 +
                    (size_t)(s & 63) * 128 + ((dc * 16) ^ ((s & 7) << 4));
      *(bf16x8*)((char*)ksw + byte) = v;
    }
  } else {
#pragma unroll
    for (int j = 0; j < 8; ++j) {
      int cidx = j * 256 + t;
      int dc = cidx & 7, drow = (cidx >> 3) & 63;
      int ktile = (cidx >> 9) & 1, h2 = cidx >> 10;
      int bh = b * 8 + hbase + h2;
      int lcol = h2 * 64 + drow;
      bf16x8 v = *(const bf16x8*)(SH + lcol * 128 +
                                  ((ktile * 64 + dc * 8) ^ ((lcol & 15) << 3)));
      size_t byte = (size_t)bh * 524288 +
                    (size_t)(((m0 & 4095) >> 6) + ktile) * 8192 +
                    (size_t)drow * 128 + ((dc * 16) ^ ((drow & 7) << 4));
      *(bf16x8*)((char*)vtsw + byte) = v;
    }
  }
}

// ---------------------------------------------------------------------------
// Flash attention, round 12: KEY-SPLIT waves.
//  Block = 4 waves = 2 q-groups x 2 key-halves; each wave: 32 q-rows x 32 keys
//  per tile. Same MFMA/exp totals as round 11 but HALF the LDS reads per wave
//  (4 b128 K-half + 4 b128 V-half). The existing kperm V layout already makes
//  the 32-key P-fragment lane-local (pi(kh*32+c*16+lhi*4+r)=kh*32+lhi*8+c*4+r).
//  Fixed-max softmax => key-halves combine additively ONCE at kernel end via
//  16KB LDS (reusing Ks after a barrier). Grid 64x16 = 4 blocks/CU.
// ---------------------------------------------------------------------------
__global__ __launch_bounds__(256, 4) void attn_kernel(
    const unsigned short* __restrict__ qp, const unsigned short* __restrict__ ksw,
    const unsigned short* __restrict__ vtsw, unsigned short* __restrict__ aout) {
  __shared__ unsigned short Ks[2][4096];     // [buf][64 key][64 d] swizzled
  __shared__ unsigned short Vts[2][4096];    // [buf][64 d][64 kperm] swizzled

  const int t = threadIdx.x, lane = t & 63, w = t >> 6;
  const int llo = lane & 15, lhi = lane >> 4;
  const int g = w >> 1;       // q-group (rows qb..qb+31)
  const int kh = w & 1;       // key half (keys kh*32..kh*32+31 of each tile)

  // XCD swizzle: 1024 blocks, 8 XCDs, 128 blocks per XCD = 2 bh each
  const int wg = blockIdx.x + (blockIdx.y << 6);
  const int pidx = ((wg & 7) << 7) + (wg >> 3);
  const int bh = pidx >> 6;
  const int q0 = (pidx & 63) * 64;
  const int qb = q0 + g * 32;

  // Q fragments: [strip][f], rows qb+strip*16+llo, d = f*32+lhi*8
  bf16x8 qf[2][2];
#pragma unroll
  for (int strip = 0; strip < 2; ++strip)
#pragma unroll
    for (int f = 0; f < 2; ++f) {
      int row = qb + strip * 16 + llo;
      int d = f * 32 + lhi * 8;
      qf[strip][f] = *(const bf16x8*)(qp + ((size_t)bh * 4096 + row) * 64 + d);
    }

  float lpart[2] = {0.f, 0.f};
  f32x4 o[2][4];   // [strip][di]
#pragma unroll
  for (int strip = 0; strip < 2; ++strip)
#pragma unroll
    for (int di = 0; di < 4; ++di) o[strip][di] = (f32x4){0.f, 0.f, 0.f, 0.f};

  const char* kbase = (const char*)ksw + (size_t)bh * 524288;
  const char* vbase = (const char*)vtsw + (size_t)bh * 524288;

  bf16x8 pf[2];   // [strip]

  auto stage_tile = [&](const char* gsrc, char* d) {
    load_lds16(gsrc + t * 16, d + t * 16);
    load_lds16(gsrc + 4096 + t * 16, d + 4096 + t * 16);
  };

  // Swapped QK^T over this wave's 32 keys: sc[strip][c][r] =
  //   S[key = kh*32 + c*16 + lhi*4 + r][q = qb + strip*16 + llo]
  auto qkt = [&](f32x4 (&sc)[2][2], const char* kbuf) {
    __builtin_amdgcn_s_setprio(1);
#pragma unroll
    for (int c = 0; c < 2; ++c) {
      int krow = kh * 32 + c * 16 + llo;
      int sw = (krow & 7) << 4;
      bf16x8 kf0 = *(const bf16x8*)(kbuf + krow * 128 + ((lhi * 16) ^ sw));
      bf16x8 kf1 = *(const bf16x8*)(kbuf + krow * 128 + ((lhi * 16 + 64) ^ sw));
#pragma unroll
      for (int strip = 0; strip < 2; ++strip) {
        sc[strip][c] = MFMA16(kf0, qf[strip][0], (f32x4){0.f, 0.f, 0.f, 0.f}, 0, 0, 0);
        sc[strip][c] = MFMA16(kf1, qf[strip][1], sc[strip][c], 0, 0, 0);
      }
    }
    __builtin_amdgcn_s_setprio(0);
  };

  // p = 2^s; P-fragment for k=32 PV: slot j = local key lhi*8 + c*4 + r
  // (kperm makes it the lane's own e[c=j>>2][r=j&3]).
  auto softmax_pack = [&](f32x4 (&sc)[2][2]) {
#pragma unroll
    for (int strip = 0; strip < 2; ++strip) {
      float e[2][4];
#pragma unroll
      for (int c = 0; c < 2; ++c)
#pragma unroll
        for (int r = 0; r < 4; ++r) {
          e[c][r] = __builtin_amdgcn_exp2f(sc[strip][c][r]);
          lpart[strip] += e[c][r];
        }
      bf16x8 pvv;
#pragma unroll
      for (int j = 0; j < 8; ++j)
        pvv[j] = __builtin_bit_cast(short,
                     __float2bfloat16(e[j >> 2][j & 3]));
      pf[strip] = pvv;
    }
  };

  // PV over this wave's 32 keys: V columns f=kh half
  auto pv_accum = [&](const char* vbuf) {
    __builtin_amdgcn_s_setprio(1);
#pragma unroll
    for (int di = 0; di < 4; ++di) {
      int vrow = di * 16 + llo;
      int byte = vrow * 128 + ((lhi * 16 + kh * 64) ^ ((vrow & 7) << 4));
      bf16x8 vf = *(const bf16x8*)(vbuf + byte);
#pragma unroll
      for (int strip = 0; strip < 2; ++strip)
        o[strip][di] = MFMA16(pf[strip], vf, o[strip][di], 0, 0, 0);
    }
    __builtin_amdgcn_s_setprio(0);
  };

  // prologue: K(0)->Ks[0], V(0)->Vts[0], K(1)->Ks[1]; then scores(0)
  stage_tile(kbase, (char*)&Ks[0][0]);
  stage_tile(vbase, (char*)&Vts[0][0]);
  stage_tile(kbase + 8192, (char*)&Ks[1][0]);
  __syncthreads();

  f32x4 scA[2][2], scB[2][2];
  qkt(scA, (const char*)&Ks[0][0]);
  __syncthreads();   // all waves done reading Ks[0] before it is overwritten

  // main loop: tiles 0..61, two per iteration (kt even)
  for (int kt = 0; kt < 62; kt += 2) {
    // tile kt (bcur=0): cur=scA, next=scB
    stage_tile(kbase + (size_t)(kt + 2) * 8192, (char*)&Ks[0][0]);
    stage_tile(vbase + (size_t)(kt + 1) * 8192, (char*)&Vts[1][0]);
    qkt(scB, (const char*)&Ks[1][0]);          // K(kt+1)
    softmax_pack(scA);                         // tile kt
    pv_accum((const char*)&Vts[0][0]);         // V(kt)
    __syncthreads();
    // tile kt+1 (bcur=1): cur=scB, next=scA
    stage_tile(kbase + (size_t)(kt + 3) * 8192, (char*)&Ks[1][0]);
    stage_tile(vbase + (size_t)(kt + 2) * 8192, (char*)&Vts[0][0]);
    qkt(scA, (const char*)&Ks[0][0]);          // K(kt+2)
    softmax_pack(scB);                         // tile kt+1
    pv_accum((const char*)&Vts[1][0]);         // V(kt+1)
    __syncthreads();
  }

  // tail: tile 62 (bcur=0)
  stage_tile(vbase + (size_t)63 * 8192, (char*)&Vts[1][0]);
  qkt(scB, (const char*)&Ks[1][0]);            // K(63)
  softmax_pack(scA);                           // tile 62
  pv_accum((const char*)&Vts[0][0]);           // V(62)
  __syncthreads();
  // tail: tile 63 (bcur=1)
  softmax_pack(scB);                           // tile 63
  pv_accum((const char*)&Vts[1][0]);           // V(63)

  // ---- cross-key-half combine via LDS (reuse Ks/Vts as f32 scratch) ----
  __syncthreads();   // everyone done with K/V LDS reads
  float* so = (float*)&Ks[0][0];     // 2 groups x 32 rows x 64 d = 16 KB
  float* sl = (float*)&Vts[0][0];    // 2 groups x 32 = 256 B

  // reduce lpart over the 4 lhi replicas (lane holds q = qb+strip*16+llo)
  float lred[2];
#pragma unroll
  for (int strip = 0; strip < 2; ++strip) {
    float s = lpart[strip];
    s += __shfl_xor(s, 16, 64);
    s += __shfl_xor(s, 32, 64);
    lred[strip] = s;
  }

  if (kh == 1) {
#pragma unroll
    for (int strip = 0; strip < 2; ++strip) {
#pragma unroll
      for (int di = 0; di < 4; ++di)
#pragma unroll
        for (int r = 0; r < 4; ++r) {
          int srow = strip * 16 + lhi * 4 + r;
          so[g * 2048 + srow * 64 + di * 16 + llo] = o[strip][di][r];
        }
      if (lhi == 0) sl[g * 32 + strip * 16 + llo] = lred[strip];
    }
  }
  __syncthreads();
  if (kh == 0) {
    float linv[2][4];
#pragma unroll
    for (int strip = 0; strip < 2; ++strip) {
      float s = lred[strip] + sl[g * 32 + strip * 16 + llo];
#pragma unroll
      for (int r = 0; r < 4; ++r)
        linv[strip][r] = 1.f / __shfl(s, lhi * 4 + r, 64);
    }
    int b = bh >> 3, h = bh & 7;
#pragma unroll
    for (int strip = 0; strip < 2; ++strip)
#pragma unroll
      for (int di = 0; di < 4; ++di)
#pragma unroll
        for (int r = 0; r < 4; ++r) {
          int srow = strip * 16 + lhi * 4 + r;
          int d = di * 16 + llo;
          float val = (o[strip][di][r] + so[g * 2048 + srow * 64 + d]) *
                      linv[strip][r];
          aout[((size_t)b * 4096 + qb + srow) * 512 + h * 64 + d] = f2bf(val);
        }
  }
}

// ---------------------------------------------------------------------------
// Output GEMM (round-8 kernel): 128x64 tiles, grid 64x8, 2-phase dbuf.
// ---------------------------------------------------------------------------
__global__ __launch_bounds__(256, 2) void out_gemm(
    const unsigned short* __restrict__ ab, const unsigned short* __restrict__ bt,
    const float* __restrict__ bias, float* __restrict__ out) {
  __shared__ unsigned short As[2][128 * 32];
  __shared__ unsigned short Bs[2][64 * 32];
  const int t = threadIdx.x;
  const int lane = t & 63;
  const int llo = lane & 15, lhi = lane >> 4;
  const int w = t >> 6;
  const int m0 = blockIdx.x * 128, n0 = blockIdx.y * 64;

  f32x4 acc[2][4];
#pragma unroll
  for (int i = 0; i < 2; ++i)
#pragma unroll
    for (int j = 0; j < 4; ++j) acc[i][j] = (f32x4){0.f, 0.f, 0.f, 0.f};

  const int r0 = t >> 2;
  const int sb = (t & 3) * 16;

  auto stage = [&](int k0, int buf) {
    const char* ga = (const char*)ab + (size_t)(m0 + r0) * 1024 + k0 * 2 + sb;
    const char* gb = (const char*)bt + (size_t)(n0 + r0) * 1024 + k0 * 2 + sb;
    load_lds16(ga, (char*)&As[buf][0] + t * 16);
    load_lds16(ga + 64 * 1024, (char*)&As[buf][0] + 4096 + t * 16);
    load_lds16(gb, (char*)&Bs[buf][0] + t * 16);
  };

  stage(0, 0);
  __syncthreads();

  int cur = 0;
  for (int k0 = 0; k0 < 512; k0 += 32) {
    if (k0 + 32 < 512) stage(k0 + 32, cur ^ 1);

    bf16x8 af[2], bf[4];
#pragma unroll
    for (int mi = 0; mi < 2; ++mi)
      af[mi] = *(const bf16x8*)(&As[cur][0] + (w * 32 + mi * 16 + llo) * 32 + lhi * 8);
#pragma unroll
    for (int ni = 0; ni < 4; ++ni)
      bf[ni] = *(const bf16x8*)(&Bs[cur][0] + (ni * 16 + llo) * 32 + lhi * 8);
#pragma unroll
    for (int mi = 0; mi < 2; ++mi)
#pragma unroll
      for (int ni = 0; ni < 4; ++ni)
        acc[mi][ni] = MFMA16(af[mi], bf[ni], acc[mi][ni], 0, 0, 0);
    __syncthreads();
    cur ^= 1;
  }

#pragma unroll
  for (int ni = 0; ni < 4; ++ni) {
    int col = n0 + ni * 16 + llo;
    float bv = bias[col];
#pragma unroll
    for (int mi = 0; mi < 2; ++mi) {
      int rowb = m0 + w * 32 + mi * 16 + lhi * 4;
#pragma unroll
      for (int r = 0; r < 4; ++r)
        out[(size_t)(rowb + r) * 512 + col] = acc[mi][ni][r] + bv;
    }
  }
}

// ---------------------------------------------------------------------------
extern "C" void kernel_launch(void* const* d_in, const int* in_sizes, int n_in,
                              void* d_out, int out_size, void* d_ws, size_t ws_size,
                              hipStream_t stream) {
  const float* x = (const float*)d_in[0];
  const float* wqkv = (const float*)d_in[1];
  const float* bqkv = (const float*)d_in[2];
  const float* wout = (const float*)d_in[3];
  const float* bout = (const float*)d_in[4];
  float* out = (float*)d_out;

  char* ws = (char*)d_ws;
  unsigned short* xb    = (unsigned short*)(ws + 0);         //  8,388,608 B
  unsigned short* wqkvT = (unsigned short*)(ws + 8388608);   //  1,572,864 B
  unsigned short* woutT = (unsigned short*)(ws + 9961472);   //    524,288 B
  unsigned short* qb    = (unsigned short*)(ws + 10485760);  //  8,388,608 B
  unsigned short* ksw   = (unsigned short*)(ws + 18874368);  //  8,388,608 B
  unsigned short* vtsw  = (unsigned short*)(ws + 27262976);  //  8,388,608 B
  unsigned short* ab    = (unsigned short*)(ws + 35651584);  //  8,388,608 B
  (void)ws_size; (void)in_sizes; (void)n_in; (void)out_size;

  prep_kernel<<<5120, 256, 0, stream>>>(x, wqkv, wout, xb, wqkvT, woutT);
  qkv_gemm<<<dim3(64, 12), 256, 0, stream>>>(xb, wqkvT, bqkv, qb, ksw, vtsw);
  attn_kernel<<<dim3(64, 16), 256, 0, stream>>>(qb, ksw, vtsw, ab);
  out_gemm<<<dim3(64, 8), 256, 0, stream>>>(ab, woutT, bout, out);
}

// Round 13
// 140.122 us; speedup vs baseline: 1.4233x; 1.4233x over previous
//
#include <hip/hip_runtime.h>
#include <hip/hip_bf16.h>

// Problem constants: B=2, S=4096, E=512, H=8, D=64
typedef __attribute__((ext_vector_type(8))) short bf16x8;
typedef __attribute__((ext_vector_type(4))) float f32x4;

#define MFMA16 __builtin_amdgcn_mfma_f32_16x16x32_bf16

__device__ __forceinline__ unsigned short f2bf(float f) {
  unsigned int u = __builtin_bit_cast(unsigned int, f);
  u += 0x7FFFu + ((u >> 16) & 1u);   // round-to-nearest-even
  return (unsigned short)(u >> 16);
}

__device__ __forceinline__ void load_lds16(const void* g, void* l) {
  __builtin_amdgcn_global_load_lds(
      (const __attribute__((address_space(1))) unsigned int*)g,
      (__attribute__((address_space(3))) unsigned int*)l, 16, 0, 0);
}

// ---------------------------------------------------------------------------
// Prep: x -> bf16 (row-major [8192][512]); w_qkv -> bf16 transposed [1536][512];
// w_out -> bf16 transposed [512][512].
// ---------------------------------------------------------------------------
__global__ __launch_bounds__(256) void prep_kernel(
    const float* __restrict__ x, const float* __restrict__ wqkv,
    const float* __restrict__ wout, unsigned short* __restrict__ xb,
    unsigned short* __restrict__ wqkvT, unsigned short* __restrict__ woutT) {
  int blk = blockIdx.x;
  int t = threadIdx.x;
  if (blk < 4096) {                       // x convert: 4,194,304 elems
    int i = (blk * 256 + t) * 4;
    float4 v = *(const float4*)(x + i);
    ushort4 o;
    o.x = f2bf(v.x); o.y = f2bf(v.y); o.z = f2bf(v.z); o.w = f2bf(v.w);
    *(ushort4*)(xb + i) = o;
  } else if (blk < 4864) {                // w_qkv transpose: 512 x 1536
    int u = ((blk - 4096) * 256 + t) * 4;
    int k = u / 1536, n = u % 1536;
    float4 v = *(const float4*)(wqkv + (size_t)k * 1536 + n);
    wqkvT[(size_t)(n + 0) * 512 + k] = f2bf(v.x);
    wqkvT[(size_t)(n + 1) * 512 + k] = f2bf(v.y);
    wqkvT[(size_t)(n + 2) * 512 + k] = f2bf(v.z);
    wqkvT[(size_t)(n + 3) * 512 + k] = f2bf(v.w);
  } else {                                // w_out transpose: 512 x 512
    int u = ((blk - 4864) * 256 + t) * 4;
    int k = u >> 9, n = u & 511;
    float4 v = *(const float4*)(wout + (size_t)k * 512 + n);
    woutT[(size_t)(n + 0) * 512 + k] = f2bf(v.x);
    woutT[(size_t)(n + 1) * 512 + k] = f2bf(v.y);
    woutT[(size_t)(n + 2) * 512 + k] = f2bf(v.z);
    woutT[(size_t)(n + 3) * 512 + k] = f2bf(v.w);
  }
}

// ---------------------------------------------------------------------------
// QKV GEMM (round-8 kernel, verified): 2-phase dbuf staging; epilogue via LDS
// transpose then 8 x 16B coalesced stores. Layouts identical to round 7.
// ---------------------------------------------------------------------------
__global__ __launch_bounds__(256, 2) void qkv_gemm(
    const unsigned short* __restrict__ xb, const unsigned short* __restrict__ bt,
    const float* __restrict__ bias, unsigned short* __restrict__ qout,
    unsigned short* __restrict__ ksw, unsigned short* __restrict__ vtsw) {
  __shared__ unsigned short SH[16384];   // 32KB: staging dbuf, then epilogue tile
  const int t = threadIdx.x;
  const int lane = t & 63;
  const int llo = lane & 15, lhi = lane >> 4;
  const int w = t >> 6, wr = w >> 1, wc = w & 1;
  const int m0 = blockIdx.x * 128, n0 = blockIdx.y * 128;

  f32x4 acc[4][4];
#pragma unroll
  for (int i = 0; i < 4; ++i)
#pragma unroll
    for (int j = 0; j < 4; ++j) acc[i][j] = (f32x4){0.f, 0.f, 0.f, 0.f};

  const int r0 = t >> 2;            // staging row (unit t)
  const int sb = (t & 3) * 16;      // byte seg within row (64B rows)

  auto stage = [&](int k0, int buf) {
    const char* ga = (const char*)xb + (size_t)(m0 + r0) * 1024 + k0 * 2 + sb;
    const char* gb = (const char*)bt + (size_t)(n0 + r0) * 1024 + k0 * 2 + sb;
    char* la = (char*)SH + buf * 8192;
    char* lb = (char*)SH + 16384 + buf * 8192;
    load_lds16(ga, la + t * 16);
    load_lds16(ga + 64 * 1024, la + 4096 + t * 16);
    load_lds16(gb, lb + t * 16);
    load_lds16(gb + 64 * 1024, lb + 4096 + t * 16);
  };

  stage(0, 0);
  __syncthreads();

  int cur = 0;
  for (int k0 = 0; k0 < 512; k0 += 32) {
    if (k0 + 32 < 512) stage(k0 + 32, cur ^ 1);

    const unsigned short* usA = SH + cur * 4096;
    const unsigned short* usB = SH + 8192 + cur * 4096;
    bf16x8 af[4], bf[4];
#pragma unroll
    for (int mi = 0; mi < 4; ++mi)
      af[mi] = *(const bf16x8*)(usA + (wr * 64 + mi * 16 + llo) * 32 + lhi * 8);
#pragma unroll
    for (int ni = 0; ni < 4; ++ni)
      bf[ni] = *(const bf16x8*)(usB + (wc * 64 + ni * 16 + llo) * 32 + lhi * 8);
#pragma unroll
    for (int mi = 0; mi < 4; ++mi)
#pragma unroll
      for (int ni = 0; ni < 4; ++ni)
        acc[mi][ni] = MFMA16(af[mi], bf[ni], acc[mi][ni], 0, 0, 0);
    __syncthreads();
    cur ^= 1;
  }

  // ---- epilogue phase 1: scatter into SH (layout-permuted, bank-swizzled) ----
  const int sec = n0 >> 9;               // 0=q, 1=K, 2=V (uniform per block)
  const int hbase = (n0 >> 6) & 7;
#pragma unroll
  for (int ni = 0; ni < 4; ++ni) {
    int lcol = wc * 64 + ni * 16 + llo;
    float bv = bias[n0 + lcol];
#pragma unroll
    for (int mi = 0; mi < 4; ++mi) {
#pragma unroll
      for (int r = 0; r < 4; ++r) {
        int rowm = wr * 64 + mi * 16 + lhi * 4 + r;
        float val = acc[mi][ni][r] + bv;
        unsigned short bits;
        int idx;
        if (sec == 0) {
          bits = f2bf(val * 0.18033688f);   // D^-0.5 * log2(e)
          idx = rowm * 128 + (lcol ^ ((rowm & 15) << 3));
        } else if (sec == 1) {
          bits = f2bf(val);
          idx = rowm * 128 + (lcol ^ ((rowm & 15) << 3));
        } else {
          bits = f2bf(val);
          int u64k = rowm & 63;
          int c = u64k >> 4, u = u64k & 15;
          int kperm = ((c >> 1) << 5) + ((u >> 2) << 3) + ((c & 1) << 2) + (u & 3);
          int ktile = rowm >> 6;
          idx = lcol * 128 + ((ktile * 64 + kperm) ^ ((lcol & 15) << 3));
        }
        SH[idx] = bits;
      }
    }
  }
  __syncthreads();

  // ---- epilogue phase 2: 8 x 16B coalesced stores per thread ----
  const int b = m0 >> 12;
  if (sec == 0) {
#pragma unroll
    for (int j = 0; j < 8; ++j) {
      int cidx = j * 256 + t;
      int dc = cidx & 7, srow = (cidx >> 3) & 127, h2 = cidx >> 10;
      int bh = b * 8 + hbase + h2;
      int s = (m0 & 4095) + srow;
      bf16x8 v = *(const bf16x8*)(SH + srow * 128 +
                                  ((h2 * 64 + dc * 8) ^ ((srow & 15) << 3)));
      *(bf16x8*)(qout + ((size_t)bh * 4096 + s) * 64 + dc * 8) = v;
    }
  } else if (sec == 1) {
#pragma unroll
    for (int j = 0; j < 8; ++j) {
      int cidx = j * 256 + t;
      int dc = cidx & 7, srow = (cidx >> 3) & 127, h2 = cidx >> 10;
      int bh = b * 8 + hbase + h2;
      int s = (m0 & 4095) + srow;
      bf16x8 v = *(const bf16x8*)(SH + srow * 128 +
                                  ((h2 * 64 + dc * 8) ^ ((srow & 15) << 3)));
      size_t byte = (size_t)bh * 524288 + (size_t)(s >> 6) * 8192 +
                    (size_t)(s & 63) * 128 + ((dc * 16) ^ ((s & 7) << 4));
      *(bf16x8*)((char*)ksw + byte) = v;
    }
  } else {
#pragma unroll
    for (int j = 0; j < 8; ++j) {
      int cidx = j * 256 + t;
      int dc = cidx & 7, drow = (cidx >> 3) & 63;
      int ktile = (cidx >> 9) & 1, h2 = cidx >> 10;
      int bh = b * 8 + hbase + h2;
      int lcol = h2 * 64 + drow;
      bf16x8 v = *(const bf16x8*)(SH + lcol * 128 +
                                  ((ktile * 64 + dc * 8) ^ ((lcol & 15) << 3)));
      size_t byte = (size_t)bh * 524288 +
                    (size_t)(((m0 & 4095) >> 6) + ktile) * 8192 +
                    (size_t)drow * 128 + ((dc * 16) ^ ((drow & 7) << 4));
      *(bf16x8*)((char*)vtsw + byte) = v;
    }
  }
}

// ---------------------------------------------------------------------------
// Flash attention, round 13 (= round 12 key-split, SPILL FIX):
//  __launch_bounds__(256, 3) instead of (256, 4) — hipcc capped (256,4)
//  kernels at 64 VGPRs (observed R9/R11/R12) forcing scratch spills
//  (R12: WRITE_SIZE 162 MB). The kernel needs ~110 VGPRs; cap >=128 keeps
//  4 waves/SIMD (occupancy step at 128) with zero spill.
//  Structure byte-identical to round 12 (correctness proven there).
// ---------------------------------------------------------------------------
__global__ __launch_bounds__(256, 3) void attn_kernel(
    const unsigned short* __restrict__ qp, const unsigned short* __restrict__ ksw,
    const unsigned short* __restrict__ vtsw, unsigned short* __restrict__ aout) {
  __shared__ unsigned short Ks[2][4096];     // [buf][64 key][64 d] swizzled
  __shared__ unsigned short Vts[2][4096];    // [buf][64 d][64 kperm] swizzled

  const int t = threadIdx.x, lane = t & 63, w = t >> 6;
  const int llo = lane & 15, lhi = lane >> 4;
  const int g = w >> 1;       // q-group (rows qb..qb+31)
  const int kh = w & 1;       // key half (keys kh*32..kh*32+31 of each tile)

  // XCD swizzle: 1024 blocks, 8 XCDs, 128 blocks per XCD = 2 bh each
  const int wg = blockIdx.x + (blockIdx.y << 6);
  const int pidx = ((wg & 7) << 7) + (wg >> 3);
  const int bh = pidx >> 6;
  const int q0 = (pidx & 63) * 64;
  const int qb = q0 + g * 32;

  // Q fragments: [strip][f], rows qb+strip*16+llo, d = f*32+lhi*8
  bf16x8 qf[2][2];
#pragma unroll
  for (int strip = 0; strip < 2; ++strip)
#pragma unroll
    for (int f = 0; f < 2; ++f) {
      int row = qb + strip * 16 + llo;
      int d = f * 32 + lhi * 8;
      qf[strip][f] = *(const bf16x8*)(qp + ((size_t)bh * 4096 + row) * 64 + d);
    }

  float lpart[2] = {0.f, 0.f};
  f32x4 o[2][4];   // [strip][di]
#pragma unroll
  for (int strip = 0; strip < 2; ++strip)
#pragma unroll
    for (int di = 0; di < 4; ++di) o[strip][di] = (f32x4){0.f, 0.f, 0.f, 0.f};

  const char* kbase = (const char*)ksw + (size_t)bh * 524288;
  const char* vbase = (const char*)vtsw + (size_t)bh * 524288;

  bf16x8 pf[2];   // [strip]

  auto stage_tile = [&](const char* gsrc, char* d) {
    load_lds16(gsrc + t * 16, d + t * 16);
    load_lds16(gsrc + 4096 + t * 16, d + 4096 + t * 16);
  };

  // Swapped QK^T over this wave's 32 keys: sc[strip][c][r] =
  //   S[key = kh*32 + c*16 + lhi*4 + r][q = qb + strip*16 + llo]
  auto qkt = [&](f32x4 (&sc)[2][2], const char* kbuf) {
    __builtin_amdgcn_s_setprio(1);
#pragma unroll
    for (int c = 0; c < 2; ++c) {
      int krow = kh * 32 + c * 16 + llo;
      int sw = (krow & 7) << 4;
      bf16x8 kf0 = *(const bf16x8*)(kbuf + krow * 128 + ((lhi * 16) ^ sw));
      bf16x8 kf1 = *(const bf16x8*)(kbuf + krow * 128 + ((lhi * 16 + 64) ^ sw));
#pragma unroll
      for (int strip = 0; strip < 2; ++strip) {
        sc[strip][c] = MFMA16(kf0, qf[strip][0], (f32x4){0.f, 0.f, 0.f, 0.f}, 0, 0, 0);
        sc[strip][c] = MFMA16(kf1, qf[strip][1], sc[strip][c], 0, 0, 0);
      }
    }
    __builtin_amdgcn_s_setprio(0);
  };

  // p = 2^s; P-fragment for k=32 PV: slot j = local key lhi*8 + c*4 + r
  // (kperm makes it the lane's own e[c=j>>2][r=j&3]).
  auto softmax_pack = [&](f32x4 (&sc)[2][2]) {
#pragma unroll
    for (int strip = 0; strip < 2; ++strip) {
      float e[2][4];
#pragma unroll
      for (int c = 0; c < 2; ++c)
#pragma unroll
        for (int r = 0; r < 4; ++r) {
          e[c][r] = __builtin_amdgcn_exp2f(sc[strip][c][r]);
          lpart[strip] += e[c][r];
        }
      bf16x8 pvv;
#pragma unroll
      for (int j = 0; j < 8; ++j)
        pvv[j] = __builtin_bit_cast(short,
                     __float2bfloat16(e[j >> 2][j & 3]));
      pf[strip] = pvv;
    }
  };

  // PV over this wave's 32 keys: V columns f=kh half
  auto pv_accum = [&](const char* vbuf) {
    __builtin_amdgcn_s_setprio(1);
#pragma unroll
    for (int di = 0; di < 4; ++di) {
      int vrow = di * 16 + llo;
      int byte = vrow * 128 + ((lhi * 16 + kh * 64) ^ ((vrow & 7) << 4));
      bf16x8 vf = *(const bf16x8*)(vbuf + byte);
#pragma unroll
      for (int strip = 0; strip < 2; ++strip)
        o[strip][di] = MFMA16(pf[strip], vf, o[strip][di], 0, 0, 0);
    }
    __builtin_amdgcn_s_setprio(0);
  };

  // prologue: K(0)->Ks[0], V(0)->Vts[0], K(1)->Ks[1]; then scores(0)
  stage_tile(kbase, (char*)&Ks[0][0]);
  stage_tile(vbase, (char*)&Vts[0][0]);
  stage_tile(kbase + 8192, (char*)&Ks[1][0]);
  __syncthreads();

  f32x4 scA[2][2], scB[2][2];
  qkt(scA, (const char*)&Ks[0][0]);
  __syncthreads();   // all waves done reading Ks[0] before it is overwritten

  // main loop: tiles 0..61, two per iteration (kt even)
  for (int kt = 0; kt < 62; kt += 2) {
    // tile kt (bcur=0): cur=scA, next=scB
    stage_tile(kbase + (size_t)(kt + 2) * 8192, (char*)&Ks[0][0]);
    stage_tile(vbase + (size_t)(kt + 1) * 8192, (char*)&Vts[1][0]);
    qkt(scB, (const char*)&Ks[1][0]);          // K(kt+1)
    softmax_pack(scA);                         // tile kt
    pv_accum((const char*)&Vts[0][0]);         // V(kt)
    __syncthreads();
    // tile kt+1 (bcur=1): cur=scB, next=scA
    stage_tile(kbase + (size_t)(kt + 3) * 8192, (char*)&Ks[1][0]);
    stage_tile(vbase + (size_t)(kt + 2) * 8192, (char*)&Vts[0][0]);
    qkt(scA, (const char*)&Ks[0][0]);          // K(kt+2)
    softmax_pack(scB);                         // tile kt+1
    pv_accum((const char*)&Vts[1][0]);         // V(kt+1)
    __syncthreads();
  }

  // tail: tile 62 (bcur=0)
  stage_tile(vbase + (size_t)63 * 8192, (char*)&Vts[1][0]);
  qkt(scB, (const char*)&Ks[1][0]);            // K(63)
  softmax_pack(scA);                           // tile 62
  pv_accum((const char*)&Vts[0][0]);           // V(62)
  __syncthreads();
  // tail: tile 63 (bcur=1)
  softmax_pack(scB);                           // tile 63
  pv_accum((const char*)&Vts[1][0]);           // V(63)

  // ---- cross-key-half combine via LDS (reuse Ks/Vts as f32 scratch) ----
  __syncthreads();   // everyone done with K/V LDS reads
  float* so = (float*)&Ks[0][0];     // 2 groups x 32 rows x 64 d = 16 KB
  float* sl = (float*)&Vts[0][0];    // 2 groups x 32 = 256 B

  // reduce lpart over the 4 lhi replicas (lane holds q = qb+strip*16+llo)
  float lred[2];
#pragma unroll
  for (int strip = 0; strip < 2; ++strip) {
    float s = lpart[strip];
    s += __shfl_xor(s, 16, 64);
    s += __shfl_xor(s, 32, 64);
    lred[strip] = s;
  }

  if (kh == 1) {
#pragma unroll
    for (int strip = 0; strip < 2; ++strip) {
#pragma unroll
      for (int di = 0; di < 4; ++di)
#pragma unroll
        for (int r = 0; r < 4; ++r) {
          int srow = strip * 16 + lhi * 4 + r;
          so[g * 2048 + srow * 64 + di * 16 + llo] = o[strip][di][r];
        }
      if (lhi == 0) sl[g * 32 + strip * 16 + llo] = lred[strip];
    }
  }
  __syncthreads();
  if (kh == 0) {
    float linv[2][4];
#pragma unroll
    for (int strip = 0; strip < 2; ++strip) {
      float s = lred[strip] + sl[g * 32 + strip * 16 + llo];
#pragma unroll
      for (int r = 0; r < 4; ++r)
        linv[strip][r] = 1.f / __shfl(s, lhi * 4 + r, 64);
    }
    int b = bh >> 3, h = bh & 7;
#pragma unroll
    for (int strip = 0; strip < 2; ++strip)
#pragma unroll
      for (int di = 0; di < 4; ++di)
#pragma unroll
        for (int r = 0; r < 4; ++r) {
          int srow = strip * 16 + lhi * 4 + r;
          int d = di * 16 + llo;
          float val = (o[strip][di][r] + so[g * 2048 + srow * 64 + d]) *
                      linv[strip][r];
          aout[((size_t)b * 4096 + qb + srow) * 512 + h * 64 + d] = f2bf(val);
        }
  }
}

// ---------------------------------------------------------------------------
// Output GEMM (round-8 kernel): 128x64 tiles, grid 64x8, 2-phase dbuf.
// ---------------------------------------------------------------------------
__global__ __launch_bounds__(256, 2) void out_gemm(
    const unsigned short* __restrict__ ab, const unsigned short* __restrict__ bt,
    const float* __restrict__ bias, float* __restrict__ out) {
  __shared__ unsigned short As[2][128 * 32];
  __shared__ unsigned short Bs[2][64 * 32];
  const int t = threadIdx.x;
  const int lane = t & 63;
  const int llo = lane & 15, lhi = lane >> 4;
  const int w = t >> 6;
  const int m0 = blockIdx.x * 128, n0 = blockIdx.y * 64;

  f32x4 acc[2][4];
#pragma unroll
  for (int i = 0; i < 2; ++i)
#pragma unroll
    for (int j = 0; j < 4; ++j) acc[i][j] = (f32x4){0.f, 0.f, 0.f, 0.f};

  const int r0 = t >> 2;
  const int sb = (t & 3) * 16;

  auto stage = [&](int k0, int buf) {
    const char* ga = (const char*)ab + (size_t)(m0 + r0) * 1024 + k0 * 2 + sb;
    const char* gb = (const char*)bt + (size_t)(n0 + r0) * 1024 + k0 * 2 + sb;
    load_lds16(ga, (char*)&As[buf][0] + t * 16);
    load_lds16(ga + 64 * 1024, (char*)&As[buf][0] + 4096 + t * 16);
    load_lds16(gb, (char*)&Bs[buf][0] + t * 16);
  };

  stage(0, 0);
  __syncthreads();

  int cur = 0;
  for (int k0 = 0; k0 < 512; k0 += 32) {
    if (k0 + 32 < 512) stage(k0 + 32, cur ^ 1);

    bf16x8 af[2], bf[4];
#pragma unroll
    for (int mi = 0; mi < 2; ++mi)
      af[mi] = *(const bf16x8*)(&As[cur][0] + (w * 32 + mi * 16 + llo) * 32 + lhi * 8);
#pragma unroll
    for (int ni = 0; ni < 4; ++ni)
      bf[ni] = *(const bf16x8*)(&Bs[cur][0] + (ni * 16 + llo) * 32 + lhi * 8);
#pragma unroll
    for (int mi = 0; mi < 2; ++mi)
#pragma unroll
      for (int ni = 0; ni < 4; ++ni)
        acc[mi][ni] = MFMA16(af[mi], bf[ni], acc[mi][ni], 0, 0, 0);
    __syncthreads();
    cur ^= 1;
  }

#pragma unroll
  for (int ni = 0; ni < 4; ++ni) {
    int col = n0 + ni * 16 + llo;
    float bv = bias[col];
#pragma unroll
    for (int mi = 0; mi < 2; ++mi) {
      int rowb = m0 + w * 32 + mi * 16 + lhi * 4;
#pragma unroll
      for (int r = 0; r < 4; ++r)
        out[(size_t)(rowb + r) * 512 + col] = acc[mi][ni][r] + bv;
    }
  }
}

// ---------------------------------------------------------------------------
extern "C" void kernel_launch(void* const* d_in, const int* in_sizes, int n_in,
                              void* d_out, int out_size, void* d_ws, size_t ws_size,
                              hipStream_t stream) {
  const float* x = (const float*)d_in[0];
  const float* wqkv = (const float*)d_in[1];
  const float* bqkv = (const float*)d_in[2];
  const float* wout = (const float*)d_in[3];
  const float* bout = (const float*)d_in[4];
  float* out = (float*)d_out;

  char* ws = (char*)d_ws;
  unsigned short* xb    = (unsigned short*)(ws + 0);         //  8,388,608 B
  unsigned short* wqkvT = (unsigned short*)(ws + 8388608);   //  1,572,864 B
  unsigned short* woutT = (unsigned short*)(ws + 9961472);   //    524,288 B
  unsigned short* qb    = (unsigned short*)(ws + 10485760);  //  8,388,608 B
  unsigned short* ksw   = (unsigned short*)(ws + 18874368);  //  8,388,608 B
  unsigned short* vtsw  = (unsigned short*)(ws + 27262976);  //  8,388,608 B
  unsigned short* ab    = (unsigned short*)(ws + 35651584);  //  8,388,608 B
  (void)ws_size; (void)in_sizes; (void)n_in; (void)out_size;

  prep_kernel<<<5120, 256, 0, stream>>>(x, wqkv, wout, xb, wqkvT, woutT);
  qkv_gemm<<<dim3(64, 12), 256, 0, stream>>>(xb, wqkvT, bqkv, qb, ksw, vtsw);
  attn_kernel<<<dim3(64, 16), 256, 0, stream>>>(qb, ksw, vtsw, ab);
  out_gemm<<<dim3(64, 8), 256, 0, stream>>>(ab, woutT, bout, out);
}

// Round 15
// 131.831 us; speedup vs baseline: 1.5128x; 1.0629x over previous
//
#include <hip/hip_runtime.h>
#include <hip/hip_bf16.h>

// Problem constants: B=2, S=4096, E=512, H=8, D=64
typedef __attribute__((ext_vector_type(8))) short bf16x8;
typedef __attribute__((ext_vector_type(4))) float f32x4;

#define MFMA16 __builtin_amdgcn_mfma_f32_16x16x32_bf16

__device__ __forceinline__ unsigned short f2bf(float f) {
  unsigned int u = __builtin_bit_cast(unsigned int, f);
  u += 0x7FFFu + ((u >> 16) & 1u);   // round-to-nearest-even
  return (unsigned short)(u >> 16);
}

__device__ __forceinline__ void load_lds16(const void* g, void* l) {
  __builtin_amdgcn_global_load_lds(
      (const __attribute__((address_space(1))) unsigned int*)g,
      (__attribute__((address_space(3))) unsigned int*)l, 16, 0, 0);
}

// ---------------------------------------------------------------------------
// Prep: x -> bf16 (row-major [8192][512]); w_qkv -> bf16 transposed [1536][512];
// w_out -> bf16 transposed [512][512].
// ---------------------------------------------------------------------------
__global__ __launch_bounds__(256) void prep_kernel(
    const float* __restrict__ x, const float* __restrict__ wqkv,
    const float* __restrict__ wout, unsigned short* __restrict__ xb,
    unsigned short* __restrict__ wqkvT, unsigned short* __restrict__ woutT) {
  int blk = blockIdx.x;
  int t = threadIdx.x;
  if (blk < 4096) {                       // x convert: 4,194,304 elems
    int i = (blk * 256 + t) * 4;
    float4 v = *(const float4*)(x + i);
    ushort4 o;
    o.x = f2bf(v.x); o.y = f2bf(v.y); o.z = f2bf(v.z); o.w = f2bf(v.w);
    *(ushort4*)(xb + i) = o;
  } else if (blk < 4864) {                // w_qkv transpose: 512 x 1536
    int u = ((blk - 4096) * 256 + t) * 4;
    int k = u / 1536, n = u % 1536;
    float4 v = *(const float4*)(wqkv + (size_t)k * 1536 + n);
    wqkvT[(size_t)(n + 0) * 512 + k] = f2bf(v.x);
    wqkvT[(size_t)(n + 1) * 512 + k] = f2bf(v.y);
    wqkvT[(size_t)(n + 2) * 512 + k] = f2bf(v.z);
    wqkvT[(size_t)(n + 3) * 512 + k] = f2bf(v.w);
  } else {                                // w_out transpose: 512 x 512
    int u = ((blk - 4864) * 256 + t) * 4;
    int k = u >> 9, n = u & 511;
    float4 v = *(const float4*)(wout + (size_t)k * 512 + n);
    woutT[(size_t)(n + 0) * 512 + k] = f2bf(v.x);
    woutT[(size_t)(n + 1) * 512 + k] = f2bf(v.y);
    woutT[(size_t)(n + 2) * 512 + k] = f2bf(v.z);
    woutT[(size_t)(n + 3) * 512 + k] = f2bf(v.w);
  }
}

// ---------------------------------------------------------------------------
// QKV GEMM, round 15 (= round 14, V-store XOR bug fixed):
//  128x64 tiles, grid 64x24 = 1536 blocks (no scheduling tail), acc[2][4].
//  Epilogue: scatter into a 16KB LDS tile; V's LDS XOR (bits 3-5) is baked
//  into the WRITE and canceled by the linear READ, so the read returns chunk
//  c' = dc ^ (drow&7) — which the global layout wants at byte dc*16 (NO
//  store-side XOR; round 14 wrongly applied it twice). q/K use a bits-4..5
//  XOR applied on write and read. Global layouts bit-identical to R8.
// ---------------------------------------------------------------------------
__global__ __launch_bounds__(256, 3) void qkv_gemm(
    const unsigned short* __restrict__ xb, const unsigned short* __restrict__ bt,
    const float* __restrict__ bias, unsigned short* __restrict__ qout,
    unsigned short* __restrict__ ksw, unsigned short* __restrict__ vtsw) {
  __shared__ unsigned short As[2][4096];   // 2 x 128x32, 16KB (epilogue reuses)
  __shared__ unsigned short Bs[2][2048];   // 2 x 64x32, 8KB
  const int t = threadIdx.x;
  const int lane = t & 63;
  const int llo = lane & 15, lhi = lane >> 4;
  const int w = t >> 6;
  const int m0 = blockIdx.x * 128, n0 = blockIdx.y * 64;

  f32x4 acc[2][4];
#pragma unroll
  for (int i = 0; i < 2; ++i)
#pragma unroll
    for (int j = 0; j < 4; ++j) acc[i][j] = (f32x4){0.f, 0.f, 0.f, 0.f};

  const int r0 = t >> 2;            // staging row
  const int sb = (t & 3) * 16;      // byte seg within 64B row

  auto stage = [&](int k0, int buf) {
    const char* ga = (const char*)xb + (size_t)(m0 + r0) * 1024 + k0 * 2 + sb;
    const char* gb = (const char*)bt + (size_t)(n0 + r0) * 1024 + k0 * 2 + sb;
    load_lds16(ga, (char*)&As[buf][0] + t * 16);
    load_lds16(ga + 64 * 1024, (char*)&As[buf][0] + 4096 + t * 16);
    load_lds16(gb, (char*)&Bs[buf][0] + t * 16);
  };

  stage(0, 0);
  __syncthreads();

  int cur = 0;
  for (int k0 = 0; k0 < 512; k0 += 32) {
    if (k0 + 32 < 512) stage(k0 + 32, cur ^ 1);

    bf16x8 af[2], bf[4];
#pragma unroll
    for (int mi = 0; mi < 2; ++mi)
      af[mi] = *(const bf16x8*)(&As[cur][0] + (w * 32 + mi * 16 + llo) * 32 + lhi * 8);
#pragma unroll
    for (int ni = 0; ni < 4; ++ni)
      bf[ni] = *(const bf16x8*)(&Bs[cur][0] + (ni * 16 + llo) * 32 + lhi * 8);
#pragma unroll
    for (int mi = 0; mi < 2; ++mi)
#pragma unroll
      for (int ni = 0; ni < 4; ++ni)
        acc[mi][ni] = MFMA16(af[mi], bf[ni], acc[mi][ni], 0, 0, 0);
    __syncthreads();
    cur ^= 1;
  }

  // ---- epilogue phase 1: scatter bf16 into 16KB LDS tile (reuse As) ----
  unsigned short* SH = &As[0][0];        // 8192 u16
  const int sec = n0 >> 9;               // 0=q, 1=K, 2=V (uniform per block)
  const int h = (n0 >> 6) & 7;
#pragma unroll
  for (int ni = 0; ni < 4; ++ni) {
    int lcol = ni * 16 + llo;            // [0,64)
    float bv = bias[n0 + lcol];
#pragma unroll
    for (int mi = 0; mi < 2; ++mi) {
#pragma unroll
      for (int r = 0; r < 4; ++r) {
        int rowm = w * 32 + mi * 16 + lhi * 4 + r;   // [0,128)
        float val = acc[mi][ni][r] + bv;
        if (sec == 0) {
          // q tile [row][64 d], XOR ((rowm>>2)&3)<<4 on write AND read
          SH[rowm * 64 + (lcol ^ (((rowm >> 2) & 3) << 4))] =
              f2bf(val * 0.18033688f);   // D^-0.5 * log2(e)
        } else if (sec == 1) {
          SH[rowm * 64 + (lcol ^ (((rowm >> 2) & 3) << 4))] = f2bf(val);
        } else {
          // V tile [d=lcol][ktile*64 + kperm], XOR (lcol&7)<<3 baked in the
          // write; linear read yields chunk c' = dc ^ (lcol&7), which the
          // global layout places at byte dc*16 (XOR cancels — see phase 2).
          int u64k = rowm & 63;
          int c = u64k >> 4, u = u64k & 15;
          int kperm = ((c >> 1) << 5) + ((u >> 2) << 3) + ((c & 1) << 2) + (u & 3);
          int ktile = rowm >> 6;
          SH[lcol * 128 + ((ktile * 64 + kperm) ^ ((lcol & 7) << 3))] = f2bf(val);
        }
      }
    }
  }
  __syncthreads();

  // ---- epilogue phase 2: 4 x 16B coalesced stores per thread ----
  const int b = m0 >> 12;
  const int bh = b * 8 + h;
  if (sec == 0) {
#pragma unroll
    for (int j = 0; j < 4; ++j) {
      int cidx = j * 256 + t;            // 128 rows x 8 chunks
      int dc = cidx & 7, srow = (cidx >> 3) & 127;
      bf16x8 v = *(const bf16x8*)(SH + srow * 64 +
                                  ((dc * 8) ^ (((srow >> 2) & 3) << 4)));
      int s = (m0 & 4095) + srow;
      *(bf16x8*)(qout + ((size_t)bh * 4096 + s) * 64 + dc * 8) = v;
    }
  } else if (sec == 1) {
#pragma unroll
    for (int j = 0; j < 4; ++j) {
      int cidx = j * 256 + t;
      int dc = cidx & 7, srow = (cidx >> 3) & 127;
      bf16x8 v = *(const bf16x8*)(SH + srow * 64 +
                                  ((dc * 8) ^ (((srow >> 2) & 3) << 4)));
      int s = (m0 & 4095) + srow;
      size_t byte = (size_t)bh * 524288 + (size_t)(s >> 6) * 8192 +
                    (size_t)(s & 63) * 128 + ((dc * 16) ^ ((s & 7) << 4));
      *(bf16x8*)((char*)ksw + byte) = v;
    }
  } else {
#pragma unroll
    for (int j = 0; j < 4; ++j) {
      int cidx = j * 256 + t;            // 2 ktile x 64 drow x 8 chunks
      int dc = cidx & 7, drow = (cidx >> 3) & 63, ktile = (cidx >> 9) & 1;
      // linear read returns chunk c' = dc ^ (drow&7) (elements c'*8+j);
      // global wants chunk c' at byte (c' ^ (drow&7))*16 = dc*16 — NO XOR here.
      bf16x8 v = *(const bf16x8*)(SH + drow * 128 + ktile * 64 + dc * 8);
      size_t byte = (size_t)bh * 524288 +
                    (size_t)(((m0 & 4095) >> 6) + ktile) * 8192 +
                    (size_t)drow * 128 + dc * 16;
      *(bf16x8*)((char*)vtsw + byte) = v;
    }
  }
}

// ---------------------------------------------------------------------------
// Flash attention (round-8 kernel, verified 87.5 us — unchanged):
//  per iteration t:  QK^T(t+1) [MFMA]  ||  softmax(t) [VALU]  ||  PV(t) [MFMA]
// ---------------------------------------------------------------------------
__global__ __launch_bounds__(256, 2) void attn_kernel(
    const unsigned short* __restrict__ qp, const unsigned short* __restrict__ ksw,
    const unsigned short* __restrict__ vtsw, unsigned short* __restrict__ aout) {
  __shared__ unsigned short Ks[2][4096];     // [buf][64 key][64 d] swizzled
  __shared__ unsigned short Vts[2][4096];    // [buf][64 d][64 kperm] swizzled

  const int t = threadIdx.x, lane = t & 63, w = t >> 6;
  const int llo = lane & 15, lhi = lane >> 4;

  // XCD swizzle: 512 blocks, 8 XCDs, 64 blocks per XCD = 2 bh each
  const int wg = blockIdx.x + (blockIdx.y << 5);
  const int pidx = ((wg & 7) << 6) + (wg >> 3);
  const int bh = pidx >> 5;
  const int q0 = (pidx & 31) * 128 + w * 32;

  // Q fragments (q pre-scaled by D^-0.5*log2e in qkv_gemm); B-operand layout
  bf16x8 qf[2][2];
#pragma unroll
  for (int qs = 0; qs < 2; ++qs)
#pragma unroll
    for (int f = 0; f < 2; ++f) {
      int row = q0 + qs * 16 + llo;
      int d = f * 32 + lhi * 8;
      qf[qs][f] = *(const bf16x8*)(qp + ((size_t)bh * 4096 + row) * 64 + d);
    }

  float lpart[2] = {0.f, 0.f};
  f32x4 o[2][4];
#pragma unroll
  for (int qs = 0; qs < 2; ++qs)
#pragma unroll
    for (int di = 0; di < 4; ++di) o[qs][di] = (f32x4){0.f, 0.f, 0.f, 0.f};

  const char* kbase = (const char*)ksw + (size_t)bh * 524288;
  const char* vbase = (const char*)vtsw + (size_t)bh * 524288;

  bf16x8 pf[2][2];

  auto stage_tile = [&](const char* g, char* d) {
    load_lds16(g + t * 16, d + t * 16);
    load_lds16(g + 4096 + t * 16, d + 4096 + t * 16);
  };

  auto qkt = [&](f32x4 (&sc)[2][4], const char* kbuf) {
    __builtin_amdgcn_s_setprio(1);
#pragma unroll
    for (int c = 0; c < 4; ++c) {
      int krow = c * 16 + llo;
      int sw = (krow & 7) << 4;
      bf16x8 kf0 = *(const bf16x8*)(kbuf + krow * 128 + ((lhi * 16) ^ sw));
      bf16x8 kf1 = *(const bf16x8*)(kbuf + krow * 128 + ((lhi * 16 + 64) ^ sw));
#pragma unroll
      for (int qs = 0; qs < 2; ++qs) {
        sc[qs][c] = MFMA16(kf0, qf[qs][0], (f32x4){0.f, 0.f, 0.f, 0.f}, 0, 0, 0);
        sc[qs][c] = MFMA16(kf1, qf[qs][1], sc[qs][c], 0, 0, 0);
      }
    }
    __builtin_amdgcn_s_setprio(0);
  };

  auto softmax_pack = [&](f32x4 (&sc)[2][4]) {
#pragma unroll
    for (int qs = 0; qs < 2; ++qs) {
      float e[4][4];
#pragma unroll
      for (int c = 0; c < 4; ++c)
#pragma unroll
        for (int r = 0; r < 4; ++r) {
          e[c][r] = __builtin_amdgcn_exp2f(sc[qs][c][r]);
          lpart[qs] += e[c][r];
        }
#pragma unroll
      for (int f = 0; f < 2; ++f) {
        bf16x8 pvv;
#pragma unroll
        for (int j = 0; j < 8; ++j)
          pvv[j] = __builtin_bit_cast(short,
                       __float2bfloat16(e[2 * f + (j >> 2)][j & 3]));
        pf[qs][f] = pvv;
      }
    }
  };

  auto pv_accum = [&](const char* vbuf) {
    __builtin_amdgcn_s_setprio(1);
#pragma unroll
    for (int f = 0; f < 2; ++f)
#pragma unroll
      for (int di = 0; di < 4; ++di) {
        int vrow = di * 16 + llo;
        int byte = vrow * 128 + ((lhi * 16 + f * 64) ^ ((vrow & 7) << 4));
        bf16x8 vf = *(const bf16x8*)(vbuf + byte);
#pragma unroll
        for (int qs = 0; qs < 2; ++qs)
          o[qs][di] = MFMA16(pf[qs][f], vf, o[qs][di], 0, 0, 0);
      }
    __builtin_amdgcn_s_setprio(0);
  };

  // prologue: K(0)->Ks[0], V(0)->Vts[0], K(1)->Ks[1]; then scores(0)
  stage_tile(kbase, (char*)&Ks[0][0]);
  stage_tile(vbase, (char*)&Vts[0][0]);
  stage_tile(kbase + 8192, (char*)&Ks[1][0]);
  __syncthreads();

  f32x4 scA[2][4], scB[2][4];
  qkt(scA, (const char*)&Ks[0][0]);
  __syncthreads();   // all waves done reading Ks[0] before it is overwritten

  // main loop: tiles 0..61, two per iteration (kt even)
  for (int kt = 0; kt < 62; kt += 2) {
    stage_tile(kbase + (size_t)(kt + 2) * 8192, (char*)&Ks[0][0]);
    stage_tile(vbase + (size_t)(kt + 1) * 8192, (char*)&Vts[1][0]);
    qkt(scB, (const char*)&Ks[1][0]);          // K(kt+1)
    softmax_pack(scA);                         // tile kt
    pv_accum((const char*)&Vts[0][0]);         // V(kt)
    __syncthreads();
    stage_tile(kbase + (size_t)(kt + 3) * 8192, (char*)&Ks[1][0]);
    stage_tile(vbase + (size_t)(kt + 2) * 8192, (char*)&Vts[0][0]);
    qkt(scA, (const char*)&Ks[0][0]);          // K(kt+2)
    softmax_pack(scB);                         // tile kt+1
    pv_accum((const char*)&Vts[1][0]);         // V(kt+1)
    __syncthreads();
  }

  // tail: tile 62
  stage_tile(vbase + (size_t)63 * 8192, (char*)&Vts[1][0]);
  qkt(scB, (const char*)&Ks[1][0]);            // K(63)
  softmax_pack(scA);                           // tile 62
  pv_accum((const char*)&Vts[0][0]);           // V(62)
  __syncthreads();
  // tail: tile 63
  softmax_pack(scB);                           // tile 63
  pv_accum((const char*)&Vts[1][0]);           // V(63)

  // deferred row-sum reduce
  float linv[2][4];
#pragma unroll
  for (int qs = 0; qs < 2; ++qs) {
    float s = lpart[qs];
    s += __shfl_xor(s, 16, 64);
    s += __shfl_xor(s, 32, 64);
#pragma unroll
    for (int r = 0; r < 4; ++r)
      linv[qs][r] = 1.f / __shfl(s, lhi * 4 + r, 64);
  }

  // epilogue: attn_out bf16 [B][S][E] with E = h*64+d
  int b = bh >> 3, h = bh & 7;
#pragma unroll
  for (int qs = 0; qs < 2; ++qs)
#pragma unroll
    for (int di = 0; di < 4; ++di)
#pragma unroll
      for (int r = 0; r < 4; ++r) {
        int s = q0 + qs * 16 + lhi * 4 + r;
        int d = di * 16 + llo;
        float val = o[qs][di][r] * linv[qs][r];
        aout[((size_t)b * 4096 + s) * 512 + h * 64 + d] = f2bf(val);
      }
}

// ---------------------------------------------------------------------------
// Output GEMM (round-8 kernel): 128x64 tiles, grid 64x8, 2-phase dbuf.
// ---------------------------------------------------------------------------
__global__ __launch_bounds__(256, 2) void out_gemm(
    const unsigned short* __restrict__ ab, const unsigned short* __restrict__ bt,
    const float* __restrict__ bias, float* __restrict__ out) {
  __shared__ unsigned short As[2][128 * 32];
  __shared__ unsigned short Bs[2][64 * 32];
  const int t = threadIdx.x;
  const int lane = t & 63;
  const int llo = lane & 15, lhi = lane >> 4;
  const int w = t >> 6;
  const int m0 = blockIdx.x * 128, n0 = blockIdx.y * 64;

  f32x4 acc[2][4];
#pragma unroll
  for (int i = 0; i < 2; ++i)
#pragma unroll
    for (int j = 0; j < 4; ++j) acc[i][j] = (f32x4){0.f, 0.f, 0.f, 0.f};

  const int r0 = t >> 2;
  const int sb = (t & 3) * 16;

  auto stage = [&](int k0, int buf) {
    const char* ga = (const char*)ab + (size_t)(m0 + r0) * 1024 + k0 * 2 + sb;
    const char* gb = (const char*)bt + (size_t)(n0 + r0) * 1024 + k0 * 2 + sb;
    load_lds16(ga, (char*)&As[buf][0] + t * 16);
    load_lds16(ga + 64 * 1024, (char*)&As[buf][0] + 4096 + t * 16);
    load_lds16(gb, (char*)&Bs[buf][0] + t * 16);
  };

  stage(0, 0);
  __syncthreads();

  int cur = 0;
  for (int k0 = 0; k0 < 512; k0 += 32) {
    if (k0 + 32 < 512) stage(k0 + 32, cur ^ 1);

    bf16x8 af[2], bf[4];
#pragma unroll
    for (int mi = 0; mi < 2; ++mi)
      af[mi] = *(const bf16x8*)(&As[cur][0] + (w * 32 + mi * 16 + llo) * 32 + lhi * 8);
#pragma unroll
    for (int ni = 0; ni < 4; ++ni)
      bf[ni] = *(const bf16x8*)(&Bs[cur][0] + (ni * 16 + llo) * 32 + lhi * 8);
#pragma unroll
    for (int mi = 0; mi < 2; ++mi)
#pragma unroll
      for (int ni = 0; ni < 4; ++ni)
        acc[mi][ni] = MFMA16(af[mi], bf[ni], acc[mi][ni], 0, 0, 0);
    __syncthreads();
    cur ^= 1;
  }

#pragma unroll
  for (int ni = 0; ni < 4; ++ni) {
    int col = n0 + ni * 16 + llo;
    float bv = bias[col];
#pragma unroll
    for (int mi = 0; mi < 2; ++mi) {
      int rowb = m0 + w * 32 + mi * 16 + lhi * 4;
#pragma unroll
      for (int r = 0; r < 4; ++r)
        out[(size_t)(rowb + r) * 512 + col] = acc[mi][ni][r] + bv;
    }
  }
}

// ---------------------------------------------------------------------------
extern "C" void kernel_launch(void* const* d_in, const int* in_sizes, int n_in,
                              void* d_out, int out_size, void* d_ws, size_t ws_size,
                              hipStream_t stream) {
  const float* x = (const float*)d_in[0];
  const float* wqkv = (const float*)d_in[1];
  const float* bqkv = (const float*)d_in[2];
  const float* wout = (const float*)d_in[3];
  const float* bout = (const float*)d_in[4];
  float* out = (float*)d_out;

  char* ws = (char*)d_ws;
  unsigned short* xb    = (unsigned short*)(ws + 0);         //  8,388,608 B
  unsigned short* wqkvT = (unsigned short*)(ws + 8388608);   //  1,572,864 B
  unsigned short* woutT = (unsigned short*)(ws + 9961472);   //    524,288 B
  unsigned short* qb    = (unsigned short*)(ws + 10485760);  //  8,388,608 B
  unsigned short* ksw   = (unsigned short*)(ws + 18874368);  //  8,388,608 B
  unsigned short* vtsw  = (unsigned short*)(ws + 27262976);  //  8,388,608 B
  unsigned short* ab    = (unsigned short*)(ws + 35651584);  //  8,388,608 B
  (void)ws_size; (void)in_sizes; (void)n_in; (void)out_size;

  prep_kernel<<<5120, 256, 0, stream>>>(x, wqkv, wout, xb, wqkvT, woutT);
  qkv_gemm<<<dim3(64, 24), 256, 0, stream>>>(xb, wqkvT, bqkv, qb, ksw, vtsw);
  attn_kernel<<<dim3(32, 16), 256, 0, stream>>>(qb, ksw, vtsw, ab);
  out_gemm<<<dim3(64, 8), 256, 0, stream>>>(ab, woutT, bout, out);
}

// Round 16
// 129.262 us; speedup vs baseline: 1.5429x; 1.0199x over previous
//
#include <hip/hip_runtime.h>
#include <hip/hip_bf16.h>

// Problem constants: B=2, S=4096, E=512, H=8, D=64
typedef __attribute__((ext_vector_type(8))) short bf16x8;
typedef __attribute__((ext_vector_type(4))) float f32x4;

#define MFMA16 __builtin_amdgcn_mfma_f32_16x16x32_bf16

__device__ __forceinline__ unsigned short f2bf(float f) {
  unsigned int u = __builtin_bit_cast(unsigned int, f);
  u += 0x7FFFu + ((u >> 16) & 1u);   // round-to-nearest-even
  return (unsigned short)(u >> 16);
}

__device__ __forceinline__ void load_lds16(const void* g, void* l) {
  __builtin_amdgcn_global_load_lds(
      (const __attribute__((address_space(1))) unsigned int*)g,
      (__attribute__((address_space(3))) unsigned int*)l, 16, 0, 0);
}

// ---------------------------------------------------------------------------
// Prep: x -> bf16 (row-major [8192][512]); w_qkv -> bf16 transposed [1536][512];
// w_out -> bf16 transposed [512][512].
// ---------------------------------------------------------------------------
__global__ __launch_bounds__(256) void prep_kernel(
    const float* __restrict__ x, const float* __restrict__ wqkv,
    const float* __restrict__ wout, unsigned short* __restrict__ xb,
    unsigned short* __restrict__ wqkvT, unsigned short* __restrict__ woutT) {
  int blk = blockIdx.x;
  int t = threadIdx.x;
  if (blk < 4096) {                       // x convert: 4,194,304 elems
    int i = (blk * 256 + t) * 4;
    float4 v = *(const float4*)(x + i);
    ushort4 o;
    o.x = f2bf(v.x); o.y = f2bf(v.y); o.z = f2bf(v.z); o.w = f2bf(v.w);
    *(ushort4*)(xb + i) = o;
  } else if (blk < 4864) {                // w_qkv transpose: 512 x 1536
    int u = ((blk - 4096) * 256 + t) * 4;
    int k = u / 1536, n = u % 1536;
    float4 v = *(const float4*)(wqkv + (size_t)k * 1536 + n);
    wqkvT[(size_t)(n + 0) * 512 + k] = f2bf(v.x);
    wqkvT[(size_t)(n + 1) * 512 + k] = f2bf(v.y);
    wqkvT[(size_t)(n + 2) * 512 + k] = f2bf(v.z);
    wqkvT[(size_t)(n + 3) * 512 + k] = f2bf(v.w);
  } else {                                // w_out transpose: 512 x 512
    int u = ((blk - 4864) * 256 + t) * 4;
    int k = u >> 9, n = u & 511;
    float4 v = *(const float4*)(wout + (size_t)k * 512 + n);
    woutT[(size_t)(n + 0) * 512 + k] = f2bf(v.x);
    woutT[(size_t)(n + 1) * 512 + k] = f2bf(v.y);
    woutT[(size_t)(n + 2) * 512 + k] = f2bf(v.z);
    woutT[(size_t)(n + 3) * 512 + k] = f2bf(v.w);
  }
}

// ---------------------------------------------------------------------------
// QKV GEMM (round-8 kernel, verified; launch_bounds 3 -> 3 blocks/CU so the
// 768-block grid runs in exactly one scheduling round, no tail):
// 128x128 tiles, 2-phase dbuf staging; epilogue via LDS transpose then
// 8 x 16B coalesced stores. Global layouts identical to round 7/8.
// ---------------------------------------------------------------------------
__global__ __launch_bounds__(256, 3) void qkv_gemm(
    const unsigned short* __restrict__ xb, const unsigned short* __restrict__ bt,
    const float* __restrict__ bias, unsigned short* __restrict__ qout,
    unsigned short* __restrict__ ksw, unsigned short* __restrict__ vtsw) {
  __shared__ unsigned short SH[16384];   // 32KB: staging dbuf, then epilogue tile
  const int t = threadIdx.x;
  const int lane = t & 63;
  const int llo = lane & 15, lhi = lane >> 4;
  const int w = t >> 6, wr = w >> 1, wc = w & 1;
  const int m0 = blockIdx.x * 128, n0 = blockIdx.y * 128;

  f32x4 acc[4][4];
#pragma unroll
  for (int i = 0; i < 4; ++i)
#pragma unroll
    for (int j = 0; j < 4; ++j) acc[i][j] = (f32x4){0.f, 0.f, 0.f, 0.f};

  const int r0 = t >> 2;            // staging row (unit t)
  const int sb = (t & 3) * 16;      // byte seg within row (64B rows)

  auto stage = [&](int k0, int buf) {
    const char* ga = (const char*)xb + (size_t)(m0 + r0) * 1024 + k0 * 2 + sb;
    const char* gb = (const char*)bt + (size_t)(n0 + r0) * 1024 + k0 * 2 + sb;
    char* la = (char*)SH + buf * 8192;
    char* lb = (char*)SH + 16384 + buf * 8192;
    load_lds16(ga, la + t * 16);
    load_lds16(ga + 64 * 1024, la + 4096 + t * 16);
    load_lds16(gb, lb + t * 16);
    load_lds16(gb + 64 * 1024, lb + 4096 + t * 16);
  };

  stage(0, 0);
  __syncthreads();

  int cur = 0;
  for (int k0 = 0; k0 < 512; k0 += 32) {
    if (k0 + 32 < 512) stage(k0 + 32, cur ^ 1);

    const unsigned short* usA = SH + cur * 4096;
    const unsigned short* usB = SH + 8192 + cur * 4096;
    bf16x8 af[4], bf[4];
#pragma unroll
    for (int mi = 0; mi < 4; ++mi)
      af[mi] = *(const bf16x8*)(usA + (wr * 64 + mi * 16 + llo) * 32 + lhi * 8);
#pragma unroll
    for (int ni = 0; ni < 4; ++ni)
      bf[ni] = *(const bf16x8*)(usB + (wc * 64 + ni * 16 + llo) * 32 + lhi * 8);
#pragma unroll
    for (int mi = 0; mi < 4; ++mi)
#pragma unroll
      for (int ni = 0; ni < 4; ++ni)
        acc[mi][ni] = MFMA16(af[mi], bf[ni], acc[mi][ni], 0, 0, 0);
    __syncthreads();
    cur ^= 1;
  }

  // ---- epilogue phase 1: scatter into SH (layout-permuted, bank-swizzled) ----
  const int sec = n0 >> 9;               // 0=q, 1=K, 2=V (uniform per block)
  const int hbase = (n0 >> 6) & 7;
#pragma unroll
  for (int ni = 0; ni < 4; ++ni) {
    int lcol = wc * 64 + ni * 16 + llo;
    float bv = bias[n0 + lcol];
#pragma unroll
    for (int mi = 0; mi < 4; ++mi) {
#pragma unroll
      for (int r = 0; r < 4; ++r) {
        int rowm = wr * 64 + mi * 16 + lhi * 4 + r;
        float val = acc[mi][ni][r] + bv;
        unsigned short bits;
        int idx;
        if (sec == 0) {
          bits = f2bf(val * 0.18033688f);   // D^-0.5 * log2(e)
          idx = rowm * 128 + (lcol ^ ((rowm & 15) << 3));
        } else if (sec == 1) {
          bits = f2bf(val);
          idx = rowm * 128 + (lcol ^ ((rowm & 15) << 3));
        } else {
          bits = f2bf(val);
          int u64k = rowm & 63;
          int c = u64k >> 4, u = u64k & 15;
          int kperm = ((c >> 1) << 5) + ((u >> 2) << 3) + ((c & 1) << 2) + (u & 3);
          int ktile = rowm >> 6;
          idx = lcol * 128 + ((ktile * 64 + kperm) ^ ((lcol & 15) << 3));
        }
        SH[idx] = bits;
      }
    }
  }
  __syncthreads();

  // ---- epilogue phase 2: 8 x 16B coalesced stores per thread ----
  const int b = m0 >> 12;
  if (sec == 0) {
#pragma unroll
    for (int j = 0; j < 8; ++j) {
      int cidx = j * 256 + t;
      int dc = cidx & 7, srow = (cidx >> 3) & 127, h2 = cidx >> 10;
      int bh = b * 8 + hbase + h2;
      int s = (m0 & 4095) + srow;
      bf16x8 v = *(const bf16x8*)(SH + srow * 128 +
                                  ((h2 * 64 + dc * 8) ^ ((srow & 15) << 3)));
      *(bf16x8*)(qout + ((size_t)bh * 4096 + s) * 64 + dc * 8) = v;
    }
  } else if (sec == 1) {
#pragma unroll
    for (int j = 0; j < 8; ++j) {
      int cidx = j * 256 + t;
      int dc = cidx & 7, srow = (cidx >> 3) & 127, h2 = cidx >> 10;
      int bh = b * 8 + hbase + h2;
      int s = (m0 & 4095) + srow;
      bf16x8 v = *(const bf16x8*)(SH + srow * 128 +
                                  ((h2 * 64 + dc * 8) ^ ((srow & 15) << 3)));
      size_t byte = (size_t)bh * 524288 + (size_t)(s >> 6) * 8192 +
                    (size_t)(s & 63) * 128 + ((dc * 16) ^ ((s & 7) << 4));
      *(bf16x8*)((char*)ksw + byte) = v;
    }
  } else {
#pragma unroll
    for (int j = 0; j < 8; ++j) {
      int cidx = j * 256 + t;
      int dc = cidx & 7, drow = (cidx >> 3) & 63;
      int ktile = (cidx >> 9) & 1, h2 = cidx >> 10;
      int bh = b * 8 + hbase + h2;
      int lcol = h2 * 64 + drow;
      bf16x8 v = *(const bf16x8*)(SH + lcol * 128 +
                                  ((ktile * 64 + dc * 8) ^ ((lcol & 15) << 3)));
      size_t byte = (size_t)bh * 524288 +
                    (size_t)(((m0 & 4095) >> 6) + ktile) * 8192 +
                    (size_t)drow * 128 + ((dc * 16) ^ ((drow & 7) << 4));
      *(bf16x8*)((char*)vtsw + byte) = v;
    }
  }
}

// ---------------------------------------------------------------------------
// Flash attention (round-8 kernel, verified 87.5 us — unchanged):
//  per iteration t:  QK^T(t+1) [MFMA]  ||  softmax(t) [VALU]  ||  PV(t) [MFMA]
// ---------------------------------------------------------------------------
__global__ __launch_bounds__(256, 2) void attn_kernel(
    const unsigned short* __restrict__ qp, const unsigned short* __restrict__ ksw,
    const unsigned short* __restrict__ vtsw, unsigned short* __restrict__ aout) {
  __shared__ unsigned short Ks[2][4096];     // [buf][64 key][64 d] swizzled
  __shared__ unsigned short Vts[2][4096];    // [buf][64 d][64 kperm] swizzled

  const int t = threadIdx.x, lane = t & 63, w = t >> 6;
  const int llo = lane & 15, lhi = lane >> 4;

  // XCD swizzle: 512 blocks, 8 XCDs, 64 blocks per XCD = 2 bh each
  const int wg = blockIdx.x + (blockIdx.y << 5);
  const int pidx = ((wg & 7) << 6) + (wg >> 3);
  const int bh = pidx >> 5;
  const int q0 = (pidx & 31) * 128 + w * 32;

  // Q fragments (q pre-scaled by D^-0.5*log2e in qkv_gemm); B-operand layout
  bf16x8 qf[2][2];
#pragma unroll
  for (int qs = 0; qs < 2; ++qs)
#pragma unroll
    for (int f = 0; f < 2; ++f) {
      int row = q0 + qs * 16 + llo;
      int d = f * 32 + lhi * 8;
      qf[qs][f] = *(const bf16x8*)(qp + ((size_t)bh * 4096 + row) * 64 + d);
    }

  float lpart[2] = {0.f, 0.f};
  f32x4 o[2][4];
#pragma unroll
  for (int qs = 0; qs < 2; ++qs)
#pragma unroll
    for (int di = 0; di < 4; ++di) o[qs][di] = (f32x4){0.f, 0.f, 0.f, 0.f};

  const char* kbase = (const char*)ksw + (size_t)bh * 524288;
  const char* vbase = (const char*)vtsw + (size_t)bh * 524288;

  bf16x8 pf[2][2];

  auto stage_tile = [&](const char* g, char* d) {
    load_lds16(g + t * 16, d + t * 16);
    load_lds16(g + 4096 + t * 16, d + 4096 + t * 16);
  };

  auto qkt = [&](f32x4 (&sc)[2][4], const char* kbuf) {
    __builtin_amdgcn_s_setprio(1);
#pragma unroll
    for (int c = 0; c < 4; ++c) {
      int krow = c * 16 + llo;
      int sw = (krow & 7) << 4;
      bf16x8 kf0 = *(const bf16x8*)(kbuf + krow * 128 + ((lhi * 16) ^ sw));
      bf16x8 kf1 = *(const bf16x8*)(kbuf + krow * 128 + ((lhi * 16 + 64) ^ sw));
#pragma unroll
      for (int qs = 0; qs < 2; ++qs) {
        sc[qs][c] = MFMA16(kf0, qf[qs][0], (f32x4){0.f, 0.f, 0.f, 0.f}, 0, 0, 0);
        sc[qs][c] = MFMA16(kf1, qf[qs][1], sc[qs][c], 0, 0, 0);
      }
    }
    __builtin_amdgcn_s_setprio(0);
  };

  auto softmax_pack = [&](f32x4 (&sc)[2][4]) {
#pragma unroll
    for (int qs = 0; qs < 2; ++qs) {
      float e[4][4];
#pragma unroll
      for (int c = 0; c < 4; ++c)
#pragma unroll
        for (int r = 0; r < 4; ++r) {
          e[c][r] = __builtin_amdgcn_exp2f(sc[qs][c][r]);
          lpart[qs] += e[c][r];
        }
#pragma unroll
      for (int f = 0; f < 2; ++f) {
        bf16x8 pvv;
#pragma unroll
        for (int j = 0; j < 8; ++j)
          pvv[j] = __builtin_bit_cast(short,
                       __float2bfloat16(e[2 * f + (j >> 2)][j & 3]));
        pf[qs][f] = pvv;
      }
    }
  };

  auto pv_accum = [&](const char* vbuf) {
    __builtin_amdgcn_s_setprio(1);
#pragma unroll
    for (int f = 0; f < 2; ++f)
#pragma unroll
      for (int di = 0; di < 4; ++di) {
        int vrow = di * 16 + llo;
        int byte = vrow * 128 + ((lhi * 16 + f * 64) ^ ((vrow & 7) << 4));
        bf16x8 vf = *(const bf16x8*)(vbuf + byte);
#pragma unroll
        for (int qs = 0; qs < 2; ++qs)
          o[qs][di] = MFMA16(pf[qs][f], vf, o[qs][di], 0, 0, 0);
      }
    __builtin_amdgcn_s_setprio(0);
  };

  // prologue: K(0)->Ks[0], V(0)->Vts[0], K(1)->Ks[1]; then scores(0)
  stage_tile(kbase, (char*)&Ks[0][0]);
  stage_tile(vbase, (char*)&Vts[0][0]);
  stage_tile(kbase + 8192, (char*)&Ks[1][0]);
  __syncthreads();

  f32x4 scA[2][4], scB[2][4];
  qkt(scA, (const char*)&Ks[0][0]);
  __syncthreads();   // all waves done reading Ks[0] before it is overwritten

  // main loop: tiles 0..61, two per iteration (kt even)
  for (int kt = 0; kt < 62; kt += 2) {
    stage_tile(kbase + (size_t)(kt + 2) * 8192, (char*)&Ks[0][0]);
    stage_tile(vbase + (size_t)(kt + 1) * 8192, (char*)&Vts[1][0]);
    qkt(scB, (const char*)&Ks[1][0]);          // K(kt+1)
    softmax_pack(scA);                         // tile kt
    pv_accum((const char*)&Vts[0][0]);         // V(kt)
    __syncthreads();
    stage_tile(kbase + (size_t)(kt + 3) * 8192, (char*)&Ks[1][0]);
    stage_tile(vbase + (size_t)(kt + 2) * 8192, (char*)&Vts[0][0]);
    qkt(scA, (const char*)&Ks[0][0]);          // K(kt+2)
    softmax_pack(scB);                         // tile kt+1
    pv_accum((const char*)&Vts[1][0]);         // V(kt+1)
    __syncthreads();
  }

  // tail: tile 62
  stage_tile(vbase + (size_t)63 * 8192, (char*)&Vts[1][0]);
  qkt(scB, (const char*)&Ks[1][0]);            // K(63)
  softmax_pack(scA);                           // tile 62
  pv_accum((const char*)&Vts[0][0]);           // V(62)
  __syncthreads();
  // tail: tile 63
  softmax_pack(scB);                           // tile 63
  pv_accum((const char*)&Vts[1][0]);           // V(63)

  // deferred row-sum reduce
  float linv[2][4];
#pragma unroll
  for (int qs = 0; qs < 2; ++qs) {
    float s = lpart[qs];
    s += __shfl_xor(s, 16, 64);
    s += __shfl_xor(s, 32, 64);
#pragma unroll
    for (int r = 0; r < 4; ++r)
      linv[qs][r] = 1.f / __shfl(s, lhi * 4 + r, 64);
  }

  // epilogue: attn_out bf16 [B][S][E] with E = h*64+d
  int b = bh >> 3, h = bh & 7;
#pragma unroll
  for (int qs = 0; qs < 2; ++qs)
#pragma unroll
    for (int di = 0; di < 4; ++di)
#pragma unroll
      for (int r = 0; r < 4; ++r) {
        int s = q0 + qs * 16 + lhi * 4 + r;
        int d = di * 16 + llo;
        float val = o[qs][di][r] * linv[qs][r];
        aout[((size_t)b * 4096 + s) * 512 + h * 64 + d] = f2bf(val);
      }
}

// ---------------------------------------------------------------------------
// Output GEMM (round-8 kernel): 128x64 tiles, grid 64x8, 2-phase dbuf.
// ---------------------------------------------------------------------------
__global__ __launch_bounds__(256, 2) void out_gemm(
    const unsigned short* __restrict__ ab, const unsigned short* __restrict__ bt,
    const float* __restrict__ bias, float* __restrict__ out) {
  __shared__ unsigned short As[2][128 * 32];
  __shared__ unsigned short Bs[2][64 * 32];
  const int t = threadIdx.x;
  const int lane = t & 63;
  const int llo = lane & 15, lhi = lane >> 4;
  const int w = t >> 6;
  const int m0 = blockIdx.x * 128, n0 = blockIdx.y * 64;

  f32x4 acc[2][4];
#pragma unroll
  for (int i = 0; i < 2; ++i)
#pragma unroll
    for (int j = 0; j < 4; ++j) acc[i][j] = (f32x4){0.f, 0.f, 0.f, 0.f};

  const int r0 = t >> 2;
  const int sb = (t & 3) * 16;

  auto stage = [&](int k0, int buf) {
    const char* ga = (const char*)ab + (size_t)(m0 + r0) * 1024 + k0 * 2 + sb;
    const char* gb = (const char*)bt + (size_t)(n0 + r0) * 1024 + k0 * 2 + sb;
    load_lds16(ga, (char*)&As[buf][0] + t * 16);
    load_lds16(ga + 64 * 1024, (char*)&As[buf][0] + 4096 + t * 16);
    load_lds16(gb, (char*)&Bs[buf][0] + t * 16);
  };

  stage(0, 0);
  __syncthreads();

  int cur = 0;
  for (int k0 = 0; k0 < 512; k0 += 32) {
    if (k0 + 32 < 512) stage(k0 + 32, cur ^ 1);

    bf16x8 af[2], bf[4];
#pragma unroll
    for (int mi = 0; mi < 2; ++mi)
      af[mi] = *(const bf16x8*)(&As[cur][0] + (w * 32 + mi * 16 + llo) * 32 + lhi * 8);
#pragma unroll
    for (int ni = 0; ni < 4; ++ni)
      bf[ni] = *(const bf16x8*)(&Bs[cur][0] + (ni * 16 + llo) * 32 + lhi * 8);
#pragma unroll
    for (int mi = 0; mi < 2; ++mi)
#pragma unroll
      for (int ni = 0; ni < 4; ++ni)
        acc[mi][ni] = MFMA16(af[mi], bf[ni], acc[mi][ni], 0, 0, 0);
    __syncthreads();
    cur ^= 1;
  }

#pragma unroll
  for (int ni = 0; ni < 4; ++ni) {
    int col = n0 + ni * 16 + llo;
    float bv = bias[col];
#pragma unroll
    for (int mi = 0; mi < 2; ++mi) {
      int rowb = m0 + w * 32 + mi * 16 + lhi * 4;
#pragma unroll
      for (int r = 0; r < 4; ++r)
        out[(size_t)(rowb + r) * 512 + col] = acc[mi][ni][r] + bv;
    }
  }
}

// ---------------------------------------------------------------------------
extern "C" void kernel_launch(void* const* d_in, const int* in_sizes, int n_in,
                              void* d_out, int out_size, void* d_ws, size_t ws_size,
                              hipStream_t stream) {
  const float* x = (const float*)d_in[0];
  const float* wqkv = (const float*)d_in[1];
  const float* bqkv = (const float*)d_in[2];
  const float* wout = (const float*)d_in[3];
  const float* bout = (const float*)d_in[4];
  float* out = (float*)d_out;

  char* ws = (char*)d_ws;
  unsigned short* xb    = (unsigned short*)(ws + 0);         //  8,388,608 B
  unsigned short* wqkvT = (unsigned short*)(ws + 8388608);   //  1,572,864 B
  unsigned short* woutT = (unsigned short*)(ws + 9961472);   //    524,288 B
  unsigned short* qb    = (unsigned short*)(ws + 10485760);  //  8,388,608 B
  unsigned short* ksw   = (unsigned short*)(ws + 18874368);  //  8,388,608 B
  unsigned short* vtsw  = (unsigned short*)(ws + 27262976);  //  8,388,608 B
  unsigned short* ab    = (unsigned short*)(ws + 35651584);  //  8,388,608 B
  (void)ws_size; (void)in_sizes; (void)n_in; (void)out_size;

  prep_kernel<<<5120, 256, 0, stream>>>(x, wqkv, wout, xb, wqkvT, woutT);
  qkv_gemm<<<dim3(64, 12), 256, 0, stream>>>(xb, wqkvT, bqkv, qb, ksw, vtsw);
  attn_kernel<<<dim3(32, 16), 256, 0, stream>>>(qb, ksw, vtsw, ab);
  out_gemm<<<dim3(64, 8), 256, 0, stream>>>(ab, woutT, bout, out);
}